// Round 10
// baseline (193.087 us; speedup 1.0000x reference)
//
#include <hip/hip_runtime.h>
#include <math.h>

#define B_ 4
#define N_ 2048
#define C_ 64
#define H_ 16
#define D_ 64
#define HID 1024

// fold attention scale (1/8) and log2(e) into Q so softmax uses exp2 directly
#define QSCALE 0.18033688011112042f  // 0.125 * 1.4426950408889634

typedef short bf16x8 __attribute__((ext_vector_type(8)));
typedef unsigned short u16x8 __attribute__((ext_vector_type(8)));
typedef float f32x4 __attribute__((ext_vector_type(4)));
typedef unsigned u32x4 __attribute__((ext_vector_type(4)));

#define MFMA(a, b, c) __builtin_amdgcn_mfma_f32_16x16x32_bf16((a), (b), (c), 0, 0, 0)

typedef __attribute__((address_space(3))) void lds_t;
typedef const __attribute__((address_space(1))) void gbl_t;
// async global->LDS, 16B/lane; LDS dest = wave-uniform base + lane*16
#define ASYNC16(g, l) __builtin_amdgcn_global_load_lds((gbl_t*)(g), (lds_t*)(l), 16, 0, 0)

static __device__ __forceinline__ unsigned short f2bf(float f) {
  unsigned u = __float_as_uint(f);
  u += 0x7FFFu + ((u >> 16) & 1u);  // round-to-nearest-even
  return (unsigned short)(u >> 16);
}
static __device__ __forceinline__ float bf2f(unsigned short h) {
  return __uint_as_float((unsigned)h << 16);
}
// pack two floats -> (bf16_trunc(a) low | bf16_trunc(b) high), single v_perm.
// Truncation bias cancels in O/l since l sums the same truncated P.
static __device__ __forceinline__ unsigned pkbf(float a, float b) {
  return __builtin_amdgcn_perm(__float_as_uint(b), __float_as_uint(a),
                               0x07060302u);
}

// ---------------------------------------------------------------------------
// Kernel 1 (Round-22, verified): QKV projection via bf16 hi/lo MFMA.
// V-transpose store PERMUTES keys within each 32-token block: position p
// holds key(p) = ((p>>2)&1)*16 + (p>>3)*4 + (p&3), matching attention's PV
// key-slot order so attn consumes P fragments directly from registers.
// ---------------------------------------------------------------------------
__global__ __launch_bounds__(256, 2) void qkv_kernel(
    const float* __restrict__ X, const float* __restrict__ W,
    const float* __restrict__ bias, const float* __restrict__ W2,
    unsigned short* __restrict__ Qhi, unsigned short* __restrict__ Khi,
    unsigned short* __restrict__ Vhi,
    unsigned short* __restrict__ W2THi, unsigned short* __restrict__ W2TLo) {
  const int t = threadIdx.x;
  const int ct = blockIdx.x;  // col tile 0..23; 24 = w2conv duty
  const int tt = blockIdx.y;  // token tile: tokens tt*128 .. +127

  if (ct == 24) {
    int idx0 = tt * 1024 + t * 4;
#pragma unroll
    for (int e = 0; e < 4; ++e) {
      int idx = idx0 + e;
      int k = idx & 1023, col = idx >> 10;
      float v = W2[(size_t)k * 64 + col];
      unsigned short hi = f2bf(v);
      W2THi[(size_t)col * 1024 + k] = hi;
      W2TLo[(size_t)col * 1024 + k] = f2bf(v - bf2f(hi));
    }
    return;
  }

  // 64 KB carved: X hi/lo [128][64], WT hi/lo [128][64]; epilogue aliases.
  __shared__ unsigned short qsmem[32768];
  unsigned short* sXhi = qsmem;           // [128][64] swizzled
  unsigned short* sXlo = qsmem + 8192;
  unsigned short* sWhi = qsmem + 16384;   // [128 cols][64 k] swizzled
  unsigned short* sWlo = qsmem + 24576;

  // ---- stage X tile (128 tokens x 64 k), fp32 -> hi/lo bf16 ----
  {
    const int kg = t & 7, r0 = t >> 3;  // kg: 8-elem k-granule, r0: 0..31
#pragma unroll
    for (int i = 0; i < 4; ++i) {
      int row = r0 + i * 32;
      const float* src = &X[(size_t)(tt * 128 + row) * 64 + kg * 8];
      f32x4 a = *(const f32x4*)src;
      f32x4 b = *(const f32x4*)(src + 4);
      u16x8 hi8, lo8;
#pragma unroll
      for (int j = 0; j < 4; ++j) {
        hi8[j] = f2bf(a[j]);
        lo8[j] = f2bf(a[j] - bf2f(hi8[j]));
        hi8[4 + j] = f2bf(b[j]);
        lo8[4 + j] = f2bf(b[j] - bf2f(hi8[4 + j]));
      }
      int off = row * 64 + ((kg ^ (row & 7)) << 3);
      *(u16x8*)&sXhi[off] = hi8;
      *(u16x8*)&sXlo[off] = lo8;
    }
  }
  // ---- stage W^T tile (128 cols x 64 k), fp32 -> hi/lo bf16 ----
  {
    const int col = t & 127, kg0 = t >> 7;  // 2 kgroups per iter pair
#pragma unroll
    for (int i = 0; i < 4; ++i) {
      int kg = kg0 + i * 2;
      u16x8 hi8, lo8;
#pragma unroll
      for (int j = 0; j < 8; ++j) {
        float v = W[(size_t)(kg * 8 + j) * 3072 + ct * 128 + col];
        unsigned short h = f2bf(v);
        hi8[j] = h;
        lo8[j] = f2bf(v - bf2f(h));
      }
      int off = col * 64 + ((kg ^ (col & 7)) << 3);
      *(u16x8*)&sWhi[off] = hi8;
      *(u16x8*)&sWlo[off] = lo8;
    }
  }
  __syncthreads();

  const int w = t >> 6, lane = t & 63;
  const int lid = lane & 15, quad = lane >> 4;

  // A fragments: wave w owns tokens w*32..+31 (2 frags of 16 rows)
  bf16x8 xa[2][2][2];  // [mt][kc][hi/lo]
#pragma unroll
  for (int mt = 0; mt < 2; ++mt) {
    int row = w * 32 + mt * 16 + lid;
#pragma unroll
    for (int kc = 0; kc < 2; ++kc) {
      int off = row * 64 + (((kc * 4 + quad) ^ (row & 7)) << 3);
      xa[mt][kc][0] = *(const bf16x8*)&sXhi[off];
      xa[mt][kc][1] = *(const bf16x8*)&sXlo[off];
    }
  }

  f32x4 acc[2][8];
#pragma unroll
  for (int mt = 0; mt < 2; ++mt)
#pragma unroll
    for (int nt = 0; nt < 8; ++nt) acc[mt][nt] = (f32x4){0.f, 0.f, 0.f, 0.f};

#pragma unroll
  for (int nt = 0; nt < 8; ++nt) {
    int col = nt * 16 + lid;
#pragma unroll
    for (int kc = 0; kc < 2; ++kc) {
      int boff = col * 64 + (((kc * 4 + quad) ^ (col & 7)) << 3);
      bf16x8 wbh = *(const bf16x8*)&sWhi[boff];
      bf16x8 wbl = *(const bf16x8*)&sWlo[boff];
#pragma unroll
      for (int mt = 0; mt < 2; ++mt) {
        f32x4 c = acc[mt][nt];
        c = MFMA(xa[mt][kc][0], wbh, c);
        c = MFMA(xa[mt][kc][0], wbl, c);
        c = MFMA(xa[mt][kc][1], wbh, c);
        acc[mt][nt] = c;
      }
    }
  }

  __syncthreads();  // all operand-tile reads done before aliasing qsmem

  const int s = ct >> 3;  // 0=q 1=k 2=v (uniform per block)
  const float scale = (s == 0) ? QSCALE : 1.0f;
  float bias_r[8];
#pragma unroll
  for (int nt = 0; nt < 8; ++nt) bias_r[nt] = bias[ct * 128 + nt * 16 + lid];

  if (s < 2) {
    // D layout: token = w*32+mt*16+quad*4+r, col = nt*16+lid
    unsigned short(*sOut)[136] = (unsigned short(*)[136])qsmem;
#pragma unroll
    for (int mt = 0; mt < 2; ++mt)
#pragma unroll
      for (int nt = 0; nt < 8; ++nt) {
        f32x4 v = acc[mt][nt];
#pragma unroll
        for (int r = 0; r < 4; ++r)
          sOut[w * 32 + mt * 16 + quad * 4 + r][nt * 16 + lid] =
              f2bf((v[r] + bias_r[nt]) * scale);
      }
    __syncthreads();
    // coalesced row stores: thread = (local token, head-half)
    const int ltok = t >> 1, half = t & 1;
    const int token = tt * 128 + ltok;
    const int bb = token >> 11, n = token & 2047;
    const int head = (ct * 2 + half) & 15;
    unsigned short* A = (s == 0) ? Qhi : Khi;
    size_t dst = ((size_t)(bb * H_ + head) * N_ + n) * D_;
    const unsigned short* srcr = &sOut[ltok][half * 64];
#pragma unroll
    for (int j = 0; j < 8; ++j)
      *(uint4*)&A[dst + j * 8] = *(const uint4*)&srcr[j * 8];
  } else {
    // V: transposed tile sT[col][pos], keys PERMUTED within 32-blocks so
    // position p holds key(p) = ((p>>2)&1)*16 + (p>>3)*4 + (p&3).
    unsigned short(*sT)[136] = (unsigned short(*)[136])qsmem;
#pragma unroll
    for (int mt = 0; mt < 2; ++mt)
#pragma unroll
      for (int nt = 0; nt < 8; ++nt) {
        f32x4 v = acc[mt][nt];
        unsigned short h0 = f2bf(v[0] + bias_r[nt]);
        unsigned short h1 = f2bf(v[1] + bias_r[nt]);
        unsigned short h2 = f2bf(v[2] + bias_r[nt]);
        unsigned short h3 = f2bf(v[3] + bias_r[nt]);
        uint2 dw;
        dw.x = (unsigned)h0 | ((unsigned)h1 << 16);
        dw.y = (unsigned)h2 | ((unsigned)h3 << 16);
        int a = mt * 4 + quad;              // 4-group index within 32-block
        int ap = ((a & 3) * 2) + (a >> 2);  // permuted group
        *(uint2*)&sT[nt * 16 + lid][w * 32 + ap * 4] = dw;
      }
    __syncthreads();
    const int col = t >> 1, half = t & 1;  // col 0..127 = (2 heads) x 64 d
    const int hv = (ct & 7) * 2 + (col >> 6), d = col & 63;
    const int bbv = tt >> 4;
    const int n0 = (tt & 15) * 128 + half * 64;
    size_t row = (size_t)((bbv * H_ + hv) * D_ + d);
    unsigned short* dstp = Vhi + row * (size_t)N_ + n0;
    const unsigned short* srcr = &sT[col][half * 64];
#pragma unroll
    for (int j = 0; j < 8; ++j)
      *(uint4*)(dstp + j * 8) = *(const uint4*)&srcr[j * 8];
  }
}

// ---------------------------------------------------------------------------
// Kernel 2: flash attention. Round-23: KVBLK 32 -> 64, double-buffered.
// R22's per-iter fixed costs (barrier, vmcnt, sched_barrier, setprio, loop
// arith) were ~30% of wall with no pipe saturated; halving iteration count
// (64 -> 32) halves them. Per-key DS cost unchanged; register-direct P
// (key-permuted V) retained; 16-MFMA setprio clusters. LDS 32 KB
// (2 x 8K K + 2 x 8K V), 4 blocks/CU, grid 1024. Dbuf discipline:
// vmcnt(0) -> s_barrier -> stage(kt+1, buf^1) -> compute(buf); prefetch
// window = 1 full iter (~1400 cy) > HBM latency.
// ---------------------------------------------------------------------------
__global__ __launch_bounds__(256, 4) void attn_kernel(
    const unsigned short* __restrict__ Qhi, const unsigned short* __restrict__ Khi,
    const unsigned short* __restrict__ VThi,
    unsigned short* __restrict__ ctxHi, unsigned short* __restrict__ ctxLo) {
  __shared__ unsigned short smem[16384];  // 32 KB: [2]K(8K) + [2]Vt(8K)

  const int tid = threadIdx.x;
  const int w = tid >> 6, lane = tid & 63;
  const int lid = lane & 15, quad = lane >> 4;
  const int l7 = lid & 7;
  unsigned short* sK = smem;          // [2][64 keys][64 d] swizzled
  unsigned short* sVt = smem + 8192;  // [2][64 d][64 keys] swizzled, permuted

  const int id = blockIdx.x;
  const int bh = id & 63;
  const int qt = id >> 6;  // 0..15
  const int b = bh >> 4, h = bh & 15;
  const size_t base = (size_t)bh * N_ * D_;
  const int row0 = qt * 128 + w * 32;

  bf16x8 qh[2][2];
#pragma unroll
  for (int mt = 0; mt < 2; ++mt) {
    int row = row0 + mt * 16 + lid;
    const unsigned short* qph = Qhi + base + (size_t)row * D_;
#pragma unroll
    for (int kc = 0; kc < 2; ++kc)
      qh[mt][kc] = *(const bf16x8*)(qph + kc * 32 + quad * 8);
  }

  f32x4 o[2][4];
  float lacc[2] = {0.f, 0.f};
#pragma unroll
  for (int mt = 0; mt < 2; ++mt)
#pragma unroll
    for (int dnt = 0; dnt < 4; ++dnt) o[mt][dnt] = (f32x4){0.f, 0.f, 0.f, 0.f};

  const int lrow = lane >> 3;         // 0..7
  const int lgr = (lane & 7) ^ lrow;  // XOR'd granule

  // stage one 64-key tile: K rows = keys, V rows = d; 2 ASYNC16 each.
  // LDS row r, granule position g holds source granule g^(r&7) (r&7 = lrow).
  auto stage = [&](int kt_, int buf_) {
#pragma unroll
    for (int i = 0; i < 2; ++i) {
      size_t gk =
          base + (size_t)(kt_ * 64 + w * 16 + i * 8 + lrow) * 64 + lgr * 8;
      ASYNC16(Khi + gk, sK + buf_ * 4096 + (w * 16 + i * 8) * 64);
    }
#pragma unroll
    for (int i = 0; i < 2; ++i) {
      int d = w * 16 + i * 8 + lrow;
      size_t gv = base + (size_t)d * N_ + kt_ * 64 + lgr * 8;
      ASYNC16(VThi + gv, sVt + buf_ * 4096 + (w * 16 + i * 8) * 64);
    }
  };

  const int NT = N_ / 64;  // 32
  stage(0, 0);

  for (int kt = 0; kt < NT; ++kt) {
    const int buf = kt & 1;
    // drain this tile's 4 loads; barrier also frees buf^1 for restage
    asm volatile("s_waitcnt vmcnt(0)" ::: "memory");
    __builtin_amdgcn_s_barrier();
    __builtin_amdgcn_sched_barrier(0);
    if (kt + 1 < NT) stage(kt + 1, buf ^ 1);

    // ---- S^T = K.Q^T (64 keys: nt 0..3) ----
    f32x4 sc[2][4];
    __builtin_amdgcn_s_setprio(1);
#pragma unroll
    for (int nt = 0; nt < 4; ++nt) {
      int key = nt * 16 + lid;
#pragma unroll
      for (int kc = 0; kc < 2; ++kc) {
        int off = buf * 4096 + key * 64 + (((kc * 4 + quad) ^ l7) << 3);
        bf16x8 kh_ = *(const bf16x8*)&sK[off];
#pragma unroll
        for (int mt = 0; mt < 2; ++mt) {
          f32x4 c = (kc == 0) ? (f32x4){0.f, 0.f, 0.f, 0.f} : sc[mt][nt];
          sc[mt][nt] = MFMA(kh_, qh[mt][kc], c);
        }
      }
    }
    __builtin_amdgcn_s_setprio(0);

    // ---- P = exp2(S) -> PV B-frags in registers (2 key-halves) ----
    bf16x8 pa[2][2];
#pragma unroll
    for (int mt = 0; mt < 2; ++mt) {
      float lsum = 0.f;
#pragma unroll
      for (int hf = 0; hf < 2; ++hf) {
        u32x4 pw;
#pragma unroll
        for (int nth = 0; nth < 2; ++nth) {
          int nt = hf * 2 + nth;
          float p0 = __builtin_amdgcn_exp2f(sc[mt][nt][0]);
          float p1 = __builtin_amdgcn_exp2f(sc[mt][nt][1]);
          float p2 = __builtin_amdgcn_exp2f(sc[mt][nt][2]);
          float p3 = __builtin_amdgcn_exp2f(sc[mt][nt][3]);
          lsum += (p0 + p1) + (p2 + p3);
          pw[nth * 2 + 0] = pkbf(p0, p1);
          pw[nth * 2 + 1] = pkbf(p2, p3);
        }
        pa[mt][hf] = __builtin_bit_cast(bf16x8, pw);
      }
      lacc[mt] += lsum;
    }

    // ---- O^T += V^T.P^T (2 key-halves) ----
    __builtin_amdgcn_s_setprio(1);
#pragma unroll
    for (int dnt = 0; dnt < 4; ++dnt) {
#pragma unroll
      for (int hf = 0; hf < 2; ++hf) {
        int voff = buf * 4096 + (dnt * 16 + lid) * 64 +
                   (((hf * 4 + quad) ^ l7) << 3);
        bf16x8 vh = *(const bf16x8*)&sVt[voff];
#pragma unroll
        for (int mt = 0; mt < 2; ++mt)
          o[mt][dnt] = MFMA(vh, pa[mt][hf], o[mt][dnt]);
      }
    }
    __builtin_amdgcn_s_setprio(0);
  }

  // ---- one-time l reduction across quads (hoisted) ----
#pragma unroll
  for (int mt = 0; mt < 2; ++mt) {
    lacc[mt] += __shfl_xor(lacc[mt], 16);
    lacc[mt] += __shfl_xor(lacc[mt], 32);
  }

  // ---- epilogue: normalize, transpose O^T via LDS, split hi/lo stores ----
  __syncthreads();
  float* scr = (float*)smem + w * 1088;  // 16 rows x 68 f32 per wave (17.4 KB)
  const int erow = lane >> 2, ecq = lane & 3;
#pragma unroll
  for (int mt = 0; mt < 2; ++mt) {
    float inv = 1.0f / lacc[mt];
#pragma unroll
    for (int dnt = 0; dnt < 4; ++dnt) {
      f32x4 v = o[mt][dnt] * inv;
      *(f32x4*)&scr[lid * 68 + dnt * 16 + quad * 4] = v;
    }
    int token = b * N_ + row0 + mt * 16 + erow;
    size_t doff = (size_t)token * HID + h * 64;
#pragma unroll
    for (int i = 0; i < 4; ++i) {
      f32x4 v4 = *(const f32x4*)&scr[erow * 68 + ecq * 4 + i * 16];
      unsigned short hi_[4], lo_[4];
#pragma unroll
      for (int j = 0; j < 4; ++j) {
        hi_[j] = f2bf(v4[j]);
        lo_[j] = f2bf(v4[j] - bf2f(hi_[j]));
      }
      uint2 hw, lw;
      hw.x = (unsigned)hi_[0] | ((unsigned)hi_[1] << 16);
      hw.y = (unsigned)hi_[2] | ((unsigned)hi_[3] << 16);
      lw.x = (unsigned)lo_[0] | ((unsigned)lo_[1] << 16);
      lw.y = (unsigned)lo_[2] | ((unsigned)lo_[3] << 16);
      *(uint2*)&ctxHi[doff + ecq * 4 + i * 16] = hw;
      *(uint2*)&ctxLo[doff + ecq * 4 + i * 16] = lw;
    }
  }
}

// ---------------------------------------------------------------------------
// Kernel 3 (Round-16): out projection via MFMA + exact GELU.
// M=8192, N=64, K=1024, 3-term hi/lo. 16 tokens/block, 4 waves each owning
// a K-quarter (256), grid 512 -> 2 blocks/CU. 4-way LDS reduction + bias +
// GELU. W2T re-read is L2-resident; ctx HBM traffic 33.5 MB read-once.
// ---------------------------------------------------------------------------
__global__ __launch_bounds__(256) void out_kernel(
    const unsigned short* __restrict__ ctxHi, const unsigned short* __restrict__ ctxLo,
    const unsigned short* __restrict__ W2THi, const unsigned short* __restrict__ W2TLo,
    const float* __restrict__ b2, float* __restrict__ out) {
  __shared__ float sO[4][4][16][16];  // [wave(k-quarter)][nt][row][lid] 16 KB
  const int tid = threadIdx.x;
  const int w = tid >> 6, lane = tid & 63;
  const int lid = lane & 15, quad = lane >> 4;
  const int tok0 = blockIdx.x * 16;

  f32x4 acc[4];
#pragma unroll
  for (int nt = 0; nt < 4; ++nt) acc[nt] = (f32x4){0.f, 0.f, 0.f, 0.f};

  // wave w covers k in [w*256, w*256+256): 8 kc steps of 32
  const size_t abase = (size_t)(tok0 + lid) * HID + w * 256 + quad * 8;

  for (int kc = 0; kc < 8; ++kc) {
    bf16x8 ah = *(const bf16x8*)&ctxHi[abase + kc * 32];
    bf16x8 al = *(const bf16x8*)&ctxLo[abase + kc * 32];
#pragma unroll
    for (int nt = 0; nt < 4; ++nt) {
      size_t boff =
          (size_t)(nt * 16 + lid) * HID + w * 256 + kc * 32 + quad * 8;
      bf16x8 bh = *(const bf16x8*)&W2THi[boff];
      bf16x8 bl = *(const bf16x8*)&W2TLo[boff];
      f32x4 c = acc[nt];
      c = MFMA(ah, bh, c);
      c = MFMA(ah, bl, c);
      c = MFMA(al, bh, c);
      acc[nt] = c;
    }
  }

  // D layout: token-local row = quad*4+r, col = nt*16+lid
#pragma unroll
  for (int nt = 0; nt < 4; ++nt)
#pragma unroll
    for (int r = 0; r < 4; ++r) sO[w][nt][quad * 4 + r][lid] = acc[nt][r];
  __syncthreads();

  // reduce 4 K-quarters: thread (w, t&63) -> rows w*4..w*4+3, col t&63
  const int col = tid & 63;
  const int nt = col >> 4, cl = col & 15;
#pragma unroll
  for (int rr = 0; rr < 4; ++rr) {
    int row = w * 4 + rr;
    float v = sO[0][nt][row][cl] + sO[1][nt][row][cl] + sO[2][nt][row][cl] +
              sO[3][nt][row][cl] + b2[col];
    float g = 0.5f * v * (1.0f + erff(v * 0.70710678118654752f));
    out[(size_t)(tok0 + row) * 64 + col] = g;
  }
}

// ---------------------------------------------------------------------------
extern "C" void kernel_launch(void* const* d_in, const int* in_sizes, int n_in,
                              void* d_out, int out_size, void* d_ws, size_t ws_size,
                              hipStream_t stream) {
  const float* X = (const float*)d_in[0];      // [4,2048,64]
  const float* qkv_w = (const float*)d_in[1];  // [64,3072]
  const float* qkv_b = (const float*)d_in[2];  // [3072]
  const float* out_w = (const float*)d_in[3];  // [1024,64]
  const float* out_b = (const float*)d_in[4];  // [64]
  float* out = (float*)d_out;

  const size_t NE = (size_t)B_ * H_ * N_ * D_;  // 8388608 elems per array
  unsigned short* ws16 = (unsigned short*)d_ws;
  unsigned short* Qhi = ws16 + 0 * NE;
  unsigned short* Khi = ws16 + 1 * NE;
  unsigned short* VThi = ws16 + 2 * NE;   // transposed [B][H][D][N], key-permuted
  unsigned short* ctxHi = ws16 + 3 * NE;  // [8192][1024] bf16
  unsigned short* ctxLo = ws16 + 4 * NE;
  unsigned short* W2THi = ws16 + 5 * NE;  // [64][1024] bf16
  unsigned short* W2TLo = W2THi + 65536;

  qkv_kernel<<<dim3(25, 64), 256, 0, stream>>>(X, qkv_w, qkv_b, out_w, Qhi,
                                               Khi, VThi, W2THi, W2TLo);
  attn_kernel<<<1024, 256, 0, stream>>>(Qhi, Khi, VThi, ctxHi, ctxLo);
  out_kernel<<<512, 256, 0, stream>>>(ctxHi, ctxLo, W2THi, W2TLo, out_b, out);
}

// Round 11
// 192.260 us; speedup vs baseline: 1.0043x; 1.0043x over previous
//
#include <hip/hip_runtime.h>
#include <math.h>

#define B_ 4
#define N_ 2048
#define C_ 64
#define H_ 16
#define D_ 64
#define HID 1024

// fold attention scale (1/8) and log2(e) into Q so softmax uses exp2 directly
#define QSCALE 0.18033688011112042f  // 0.125 * 1.4426950408889634

typedef short bf16x8 __attribute__((ext_vector_type(8)));
typedef unsigned short u16x8 __attribute__((ext_vector_type(8)));
typedef float f32x4 __attribute__((ext_vector_type(4)));
typedef unsigned u32x4 __attribute__((ext_vector_type(4)));

#define MFMA(a, b, c) __builtin_amdgcn_mfma_f32_16x16x32_bf16((a), (b), (c), 0, 0, 0)

typedef __attribute__((address_space(3))) void lds_t;
typedef const __attribute__((address_space(1))) void gbl_t;
// async global->LDS, 16B/lane; LDS dest = wave-uniform base + lane*16
#define ASYNC16(g, l) __builtin_amdgcn_global_load_lds((gbl_t*)(g), (lds_t*)(l), 16, 0, 0)

static __device__ __forceinline__ unsigned short f2bf(float f) {
  unsigned u = __float_as_uint(f);
  u += 0x7FFFu + ((u >> 16) & 1u);  // round-to-nearest-even
  return (unsigned short)(u >> 16);
}
static __device__ __forceinline__ float bf2f(unsigned short h) {
  return __uint_as_float((unsigned)h << 16);
}
// pack two floats -> (bf16_trunc(a) low | bf16_trunc(b) high), single v_perm.
// Truncation bias cancels in O/l since l sums the same truncated P.
static __device__ __forceinline__ unsigned pkbf(float a, float b) {
  return __builtin_amdgcn_perm(__float_as_uint(b), __float_as_uint(a),
                               0x07060302u);
}

// ---------------------------------------------------------------------------
// Kernel 1 (Round-22, verified): QKV projection via bf16 hi/lo MFMA.
// V-transpose store PERMUTES keys within each 32-token block: position p
// holds key(p) = ((p>>2)&1)*16 + (p>>3)*4 + (p&3), matching attention's PV
// key-slot order so attn consumes P fragments directly from registers.
// ---------------------------------------------------------------------------
__global__ __launch_bounds__(256, 2) void qkv_kernel(
    const float* __restrict__ X, const float* __restrict__ W,
    const float* __restrict__ bias, const float* __restrict__ W2,
    unsigned short* __restrict__ Qhi, unsigned short* __restrict__ Khi,
    unsigned short* __restrict__ Vhi,
    unsigned short* __restrict__ W2THi, unsigned short* __restrict__ W2TLo) {
  const int t = threadIdx.x;
  const int ct = blockIdx.x;  // col tile 0..23; 24 = w2conv duty
  const int tt = blockIdx.y;  // token tile: tokens tt*128 .. +127

  if (ct == 24) {
    int idx0 = tt * 1024 + t * 4;
#pragma unroll
    for (int e = 0; e < 4; ++e) {
      int idx = idx0 + e;
      int k = idx & 1023, col = idx >> 10;
      float v = W2[(size_t)k * 64 + col];
      unsigned short hi = f2bf(v);
      W2THi[(size_t)col * 1024 + k] = hi;
      W2TLo[(size_t)col * 1024 + k] = f2bf(v - bf2f(hi));
    }
    return;
  }

  // 64 KB carved: X hi/lo [128][64], WT hi/lo [128][64]; epilogue aliases.
  __shared__ unsigned short qsmem[32768];
  unsigned short* sXhi = qsmem;           // [128][64] swizzled
  unsigned short* sXlo = qsmem + 8192;
  unsigned short* sWhi = qsmem + 16384;   // [128 cols][64 k] swizzled
  unsigned short* sWlo = qsmem + 24576;

  // ---- stage X tile (128 tokens x 64 k), fp32 -> hi/lo bf16 ----
  {
    const int kg = t & 7, r0 = t >> 3;  // kg: 8-elem k-granule, r0: 0..31
#pragma unroll
    for (int i = 0; i < 4; ++i) {
      int row = r0 + i * 32;
      const float* src = &X[(size_t)(tt * 128 + row) * 64 + kg * 8];
      f32x4 a = *(const f32x4*)src;
      f32x4 b = *(const f32x4*)(src + 4);
      u16x8 hi8, lo8;
#pragma unroll
      for (int j = 0; j < 4; ++j) {
        hi8[j] = f2bf(a[j]);
        lo8[j] = f2bf(a[j] - bf2f(hi8[j]));
        hi8[4 + j] = f2bf(b[j]);
        lo8[4 + j] = f2bf(b[j] - bf2f(hi8[4 + j]));
      }
      int off = row * 64 + ((kg ^ (row & 7)) << 3);
      *(u16x8*)&sXhi[off] = hi8;
      *(u16x8*)&sXlo[off] = lo8;
    }
  }
  // ---- stage W^T tile (128 cols x 64 k), fp32 -> hi/lo bf16 ----
  {
    const int col = t & 127, kg0 = t >> 7;  // 2 kgroups per iter pair
#pragma unroll
    for (int i = 0; i < 4; ++i) {
      int kg = kg0 + i * 2;
      u16x8 hi8, lo8;
#pragma unroll
      for (int j = 0; j < 8; ++j) {
        float v = W[(size_t)(kg * 8 + j) * 3072 + ct * 128 + col];
        unsigned short h = f2bf(v);
        hi8[j] = h;
        lo8[j] = f2bf(v - bf2f(h));
      }
      int off = col * 64 + ((kg ^ (col & 7)) << 3);
      *(u16x8*)&sWhi[off] = hi8;
      *(u16x8*)&sWlo[off] = lo8;
    }
  }
  __syncthreads();

  const int w = t >> 6, lane = t & 63;
  const int lid = lane & 15, quad = lane >> 4;

  // A fragments: wave w owns tokens w*32..+31 (2 frags of 16 rows)
  bf16x8 xa[2][2][2];  // [mt][kc][hi/lo]
#pragma unroll
  for (int mt = 0; mt < 2; ++mt) {
    int row = w * 32 + mt * 16 + lid;
#pragma unroll
    for (int kc = 0; kc < 2; ++kc) {
      int off = row * 64 + (((kc * 4 + quad) ^ (row & 7)) << 3);
      xa[mt][kc][0] = *(const bf16x8*)&sXhi[off];
      xa[mt][kc][1] = *(const bf16x8*)&sXlo[off];
    }
  }

  f32x4 acc[2][8];
#pragma unroll
  for (int mt = 0; mt < 2; ++mt)
#pragma unroll
    for (int nt = 0; nt < 8; ++nt) acc[mt][nt] = (f32x4){0.f, 0.f, 0.f, 0.f};

#pragma unroll
  for (int nt = 0; nt < 8; ++nt) {
    int col = nt * 16 + lid;
#pragma unroll
    for (int kc = 0; kc < 2; ++kc) {
      int boff = col * 64 + (((kc * 4 + quad) ^ (col & 7)) << 3);
      bf16x8 wbh = *(const bf16x8*)&sWhi[boff];
      bf16x8 wbl = *(const bf16x8*)&sWlo[boff];
#pragma unroll
      for (int mt = 0; mt < 2; ++mt) {
        f32x4 c = acc[mt][nt];
        c = MFMA(xa[mt][kc][0], wbh, c);
        c = MFMA(xa[mt][kc][0], wbl, c);
        c = MFMA(xa[mt][kc][1], wbh, c);
        acc[mt][nt] = c;
      }
    }
  }

  __syncthreads();  // all operand-tile reads done before aliasing qsmem

  const int s = ct >> 3;  // 0=q 1=k 2=v (uniform per block)
  const float scale = (s == 0) ? QSCALE : 1.0f;
  float bias_r[8];
#pragma unroll
  for (int nt = 0; nt < 8; ++nt) bias_r[nt] = bias[ct * 128 + nt * 16 + lid];

  if (s < 2) {
    // D layout: token = w*32+mt*16+quad*4+r, col = nt*16+lid
    unsigned short(*sOut)[136] = (unsigned short(*)[136])qsmem;
#pragma unroll
    for (int mt = 0; mt < 2; ++mt)
#pragma unroll
      for (int nt = 0; nt < 8; ++nt) {
        f32x4 v = acc[mt][nt];
#pragma unroll
        for (int r = 0; r < 4; ++r)
          sOut[w * 32 + mt * 16 + quad * 4 + r][nt * 16 + lid] =
              f2bf((v[r] + bias_r[nt]) * scale);
      }
    __syncthreads();
    // coalesced row stores: thread = (local token, head-half)
    const int ltok = t >> 1, half = t & 1;
    const int token = tt * 128 + ltok;
    const int bb = token >> 11, n = token & 2047;
    const int head = (ct * 2 + half) & 15;
    unsigned short* A = (s == 0) ? Qhi : Khi;
    size_t dst = ((size_t)(bb * H_ + head) * N_ + n) * D_;
    const unsigned short* srcr = &sOut[ltok][half * 64];
#pragma unroll
    for (int j = 0; j < 8; ++j)
      *(uint4*)&A[dst + j * 8] = *(const uint4*)&srcr[j * 8];
  } else {
    // V: transposed tile sT[col][pos], keys PERMUTED within 32-blocks so
    // position p holds key(p) = ((p>>2)&1)*16 + (p>>3)*4 + (p&3).
    unsigned short(*sT)[136] = (unsigned short(*)[136])qsmem;
#pragma unroll
    for (int mt = 0; mt < 2; ++mt)
#pragma unroll
      for (int nt = 0; nt < 8; ++nt) {
        f32x4 v = acc[mt][nt];
        unsigned short h0 = f2bf(v[0] + bias_r[nt]);
        unsigned short h1 = f2bf(v[1] + bias_r[nt]);
        unsigned short h2 = f2bf(v[2] + bias_r[nt]);
        unsigned short h3 = f2bf(v[3] + bias_r[nt]);
        uint2 dw;
        dw.x = (unsigned)h0 | ((unsigned)h1 << 16);
        dw.y = (unsigned)h2 | ((unsigned)h3 << 16);
        int a = mt * 4 + quad;              // 4-group index within 32-block
        int ap = ((a & 3) * 2) + (a >> 2);  // permuted group
        *(uint2*)&sT[nt * 16 + lid][w * 32 + ap * 4] = dw;
      }
    __syncthreads();
    const int col = t >> 1, half = t & 1;  // col 0..127 = (2 heads) x 64 d
    const int hv = (ct & 7) * 2 + (col >> 6), d = col & 63;
    const int bbv = tt >> 4;
    const int n0 = (tt & 15) * 128 + half * 64;
    size_t row = (size_t)((bbv * H_ + hv) * D_ + d);
    unsigned short* dstp = Vhi + row * (size_t)N_ + n0;
    const unsigned short* srcr = &sT[col][half * 64];
#pragma unroll
    for (int j = 0; j < 8; ++j)
      *(uint4*)(dstp + j * 8) = *(const uint4*)&srcr[j * 8];
  }
}

// ---------------------------------------------------------------------------
// Kernel 2: flash attention. Round-24: cross-iteration software pipeline.
// R23 sat at the 2-barrier lockstep ceiling (~886 TF): per iteration every
// wave ran S -> exp2 -> PV serially, idling MFMA during softmax and VALU
// during MFMA. Now S(kt+1) and PV(kt) execute in the same phase window
// (independent: PV uses paX from the previous iteration's P). KVBLK=32,
// FOUR LDS buffers (buf = kt&3, 32 KB total, 4 blocks/CU kept), 3-ahead
// staging with counted vmcnt(2) (tile kt+2 stays in flight across the
// barrier; only the S-target tile is drained). stage() is issued after the
// barrier (R17 discipline: prior readers' ds_reads are register-consumed
// pre-barrier via MFMA lgkm dependency). P double-buffers in named paA/paB
// with a 2-unrolled loop (rule #20). Register-direct P (key-permuted V)
// retained. NT=64 (even).
// ---------------------------------------------------------------------------
__global__ __launch_bounds__(256, 4) void attn_kernel(
    const unsigned short* __restrict__ Qhi, const unsigned short* __restrict__ Khi,
    const unsigned short* __restrict__ VThi,
    unsigned short* __restrict__ ctxHi, unsigned short* __restrict__ ctxLo) {
  __shared__ unsigned short smem[16384];  // 32 KB: [4]K(4K) + [4]Vt(4K)

  const int tid = threadIdx.x;
  const int w = tid >> 6, lane = tid & 63;
  const int lid = lane & 15, quad = lane >> 4;
  const int l7 = lid & 7;
  unsigned short* sK = smem;          // [4][32 keys][64 d] swizzled
  unsigned short* sVt = smem + 8192;  // [4][64 d][32 keys] row-paired, permuted

  const int id = blockIdx.x;
  const int bh = id & 63;
  const int qt = id >> 6;  // 0..15
  const int b = bh >> 4, h = bh & 15;
  const size_t base = (size_t)bh * N_ * D_;
  const int row0 = qt * 128 + w * 32;

  bf16x8 qh[2][2];
#pragma unroll
  for (int mt = 0; mt < 2; ++mt) {
    int row = row0 + mt * 16 + lid;
    const unsigned short* qph = Qhi + base + (size_t)row * D_;
#pragma unroll
    for (int kc = 0; kc < 2; ++kc)
      qh[mt][kc] = *(const bf16x8*)(qph + kc * 32 + quad * 8);
  }

  f32x4 o[2][4];
  float lacc[2] = {0.f, 0.f};
#pragma unroll
  for (int mt = 0; mt < 2; ++mt)
#pragma unroll
    for (int dnt = 0; dnt < 4; ++dnt) o[mt][dnt] = (f32x4){0.f, 0.f, 0.f, 0.f};

  const int lrow = lane >> 3;         // 0..7
  const int lgr = (lane & 7) ^ lrow;  // XOR'd granule

  auto stage = [&](int kt_, int buf_) {
    size_t gk = base + (size_t)(kt_ * 32 + w * 8 + lrow) * 64 + lgr * 8;
    ASYNC16(Khi + gk, sK + buf_ * 2048 + (w * 8) * 64);
    int pr = w * 8 + lrow;
    int vd = pr * 2 + (lgr >> 2);
    int vk0 = (lgr & 3) * 8;
    size_t gv = base + (size_t)vd * N_ + kt_ * 32 + vk0;
    ASYNC16(VThi + gv, sVt + buf_ * 2048 + (w * 8) * 64);
  };

  // S^T = K.Q^T for one 32-key tile (buf) -> sc
  auto doS = [&](int buf, f32x4 (&sc)[2][2]) {
#pragma unroll
    for (int nt = 0; nt < 2; ++nt) {
      int key = nt * 16 + lid;
#pragma unroll
      for (int kc = 0; kc < 2; ++kc) {
        int off = buf * 2048 + key * 64 + (((kc * 4 + quad) ^ l7) << 3);
        bf16x8 kh_ = *(const bf16x8*)&sK[off];
#pragma unroll
        for (int mt = 0; mt < 2; ++mt) {
          f32x4 c = (kc == 0) ? (f32x4){0.f, 0.f, 0.f, 0.f} : sc[mt][nt];
          sc[mt][nt] = MFMA(kh_, qh[mt][kc], c);
        }
      }
    }
  };

  // P = exp2(S) -> register-direct PV B-frags + lane-local l accumulation
  auto doP = [&](f32x4 (&sc)[2][2], bf16x8 (&pa)[2]) {
#pragma unroll
    for (int mt = 0; mt < 2; ++mt) {
      float lsum = 0.f;
      u32x4 pw;
#pragma unroll
      for (int nt = 0; nt < 2; ++nt) {
        float p0 = __builtin_amdgcn_exp2f(sc[mt][nt][0]);
        float p1 = __builtin_amdgcn_exp2f(sc[mt][nt][1]);
        float p2 = __builtin_amdgcn_exp2f(sc[mt][nt][2]);
        float p3 = __builtin_amdgcn_exp2f(sc[mt][nt][3]);
        lsum += (p0 + p1) + (p2 + p3);
        pw[nt * 2 + 0] = pkbf(p0, p1);
        pw[nt * 2 + 1] = pkbf(p2, p3);
      }
      lacc[mt] += lsum;
      pa[mt] = __builtin_bit_cast(bf16x8, pw);
    }
  };

  // O^T += V^T.P^T for one tile (buf)
  auto doPV = [&](int buf, bf16x8 (&pa)[2]) {
#pragma unroll
    for (int dnt = 0; dnt < 4; ++dnt) {
      int voff = buf * 2048 + (dnt * 8 + (lid >> 1)) * 64 +
                 (((quad + (lid & 1) * 4) ^ ((lid >> 1) & 7)) << 3);
      bf16x8 vh = *(const bf16x8*)&sVt[voff];
#pragma unroll
      for (int mt = 0; mt < 2; ++mt) o[mt][dnt] = MFMA(vh, pa[mt], o[mt][dnt]);
    }
  };

  const int NT = N_ / 32;  // 64
  stage(0, 0);
  stage(1, 1);
  stage(2, 2);
  asm volatile("s_waitcnt vmcnt(4)" ::: "memory");  // tile 0 landed
  __builtin_amdgcn_s_barrier();
  __builtin_amdgcn_sched_barrier(0);

  f32x4 sc[2][2];
  bf16x8 paA[2], paB[2];
  doS(0, sc);
  doP(sc, paA);

  for (int kt = 0; kt < NT; kt += 2) {
    // ---- sub-iter A: S(kt+1) || PV(kt) ----
    if (kt + 2 < NT)
      asm volatile("s_waitcnt vmcnt(2)" ::: "memory");  // drain tile kt+1
    else
      asm volatile("s_waitcnt vmcnt(0)" ::: "memory");
    __builtin_amdgcn_s_barrier();
    __builtin_amdgcn_sched_barrier(0);
    if (kt + 3 < NT) stage(kt + 3, (kt + 3) & 3);
    __builtin_amdgcn_s_setprio(1);
    doS((kt + 1) & 3, sc);
    doPV(kt & 3, paA);
    __builtin_amdgcn_s_setprio(0);
    doP(sc, paB);

    // ---- sub-iter B: S(kt+2) || PV(kt+1) ----
    if (kt + 3 < NT)
      asm volatile("s_waitcnt vmcnt(2)" ::: "memory");  // drain tile kt+2
    else
      asm volatile("s_waitcnt vmcnt(0)" ::: "memory");
    __builtin_amdgcn_s_barrier();
    __builtin_amdgcn_sched_barrier(0);
    if (kt + 4 < NT) stage(kt + 4, (kt + 4) & 3);
    __builtin_amdgcn_s_setprio(1);
    if (kt + 2 < NT) doS((kt + 2) & 3, sc);
    doPV((kt + 1) & 3, paB);
    __builtin_amdgcn_s_setprio(0);
    if (kt + 2 < NT) doP(sc, paA);
  }

  // ---- one-time l reduction across quads (hoisted) ----
#pragma unroll
  for (int mt = 0; mt < 2; ++mt) {
    lacc[mt] += __shfl_xor(lacc[mt], 16);
    lacc[mt] += __shfl_xor(lacc[mt], 32);
  }

  // ---- epilogue: normalize, transpose O^T via LDS, split hi/lo stores ----
  __syncthreads();
  float* scr = (float*)smem + w * 1088;  // 16 rows x 68 f32 per wave (17.4 KB)
  const int erow = lane >> 2, ecq = lane & 3;
#pragma unroll
  for (int mt = 0; mt < 2; ++mt) {
    float inv = 1.0f / lacc[mt];
#pragma unroll
    for (int dnt = 0; dnt < 4; ++dnt) {
      f32x4 v = o[mt][dnt] * inv;
      *(f32x4*)&scr[lid * 68 + dnt * 16 + quad * 4] = v;
    }
    int token = b * N_ + row0 + mt * 16 + erow;
    size_t doff = (size_t)token * HID + h * 64;
#pragma unroll
    for (int i = 0; i < 4; ++i) {
      f32x4 v4 = *(const f32x4*)&scr[erow * 68 + ecq * 4 + i * 16];
      unsigned short hi_[4], lo_[4];
#pragma unroll
      for (int j = 0; j < 4; ++j) {
        hi_[j] = f2bf(v4[j]);
        lo_[j] = f2bf(v4[j] - bf2f(hi_[j]));
      }
      uint2 hw, lw;
      hw.x = (unsigned)hi_[0] | ((unsigned)hi_[1] << 16);
      hw.y = (unsigned)hi_[2] | ((unsigned)hi_[3] << 16);
      lw.x = (unsigned)lo_[0] | ((unsigned)lo_[1] << 16);
      lw.y = (unsigned)lo_[2] | ((unsigned)lo_[3] << 16);
      *(uint2*)&ctxHi[doff + ecq * 4 + i * 16] = hw;
      *(uint2*)&ctxLo[doff + ecq * 4 + i * 16] = lw;
    }
  }
}

// ---------------------------------------------------------------------------
// Kernel 3 (Round-16): out projection via MFMA + exact GELU.
// M=8192, N=64, K=1024, 3-term hi/lo. 16 tokens/block, 4 waves each owning
// a K-quarter (256), grid 512 -> 2 blocks/CU. 4-way LDS reduction + bias +
// GELU. W2T re-read is L2-resident; ctx HBM traffic 33.5 MB read-once.
// ---------------------------------------------------------------------------
__global__ __launch_bounds__(256) void out_kernel(
    const unsigned short* __restrict__ ctxHi, const unsigned short* __restrict__ ctxLo,
    const unsigned short* __restrict__ W2THi, const unsigned short* __restrict__ W2TLo,
    const float* __restrict__ b2, float* __restrict__ out) {
  __shared__ float sO[4][4][16][16];  // [wave(k-quarter)][nt][row][lid] 16 KB
  const int tid = threadIdx.x;
  const int w = tid >> 6, lane = tid & 63;
  const int lid = lane & 15, quad = lane >> 4;
  const int tok0 = blockIdx.x * 16;

  f32x4 acc[4];
#pragma unroll
  for (int nt = 0; nt < 4; ++nt) acc[nt] = (f32x4){0.f, 0.f, 0.f, 0.f};

  // wave w covers k in [w*256, w*256+256): 8 kc steps of 32
  const size_t abase = (size_t)(tok0 + lid) * HID + w * 256 + quad * 8;

  for (int kc = 0; kc < 8; ++kc) {
    bf16x8 ah = *(const bf16x8*)&ctxHi[abase + kc * 32];
    bf16x8 al = *(const bf16x8*)&ctxLo[abase + kc * 32];
#pragma unroll
    for (int nt = 0; nt < 4; ++nt) {
      size_t boff =
          (size_t)(nt * 16 + lid) * HID + w * 256 + kc * 32 + quad * 8;
      bf16x8 bh = *(const bf16x8*)&W2THi[boff];
      bf16x8 bl = *(const bf16x8*)&W2TLo[boff];
      f32x4 c = acc[nt];
      c = MFMA(ah, bh, c);
      c = MFMA(ah, bl, c);
      c = MFMA(al, bh, c);
      acc[nt] = c;
    }
  }

  // D layout: token-local row = quad*4+r, col = nt*16+lid
#pragma unroll
  for (int nt = 0; nt < 4; ++nt)
#pragma unroll
    for (int r = 0; r < 4; ++r) sO[w][nt][quad * 4 + r][lid] = acc[nt][r];
  __syncthreads();

  // reduce 4 K-quarters: thread (w, t&63) -> rows w*4..w*4+3, col t&63
  const int col = tid & 63;
  const int nt = col >> 4, cl = col & 15;
#pragma unroll
  for (int rr = 0; rr < 4; ++rr) {
    int row = w * 4 + rr;
    float v = sO[0][nt][row][cl] + sO[1][nt][row][cl] + sO[2][nt][row][cl] +
              sO[3][nt][row][cl] + b2[col];
    float g = 0.5f * v * (1.0f + erff(v * 0.70710678118654752f));
    out[(size_t)(tok0 + row) * 64 + col] = g;
  }
}

// ---------------------------------------------------------------------------
extern "C" void kernel_launch(void* const* d_in, const int* in_sizes, int n_in,
                              void* d_out, int out_size, void* d_ws, size_t ws_size,
                              hipStream_t stream) {
  const float* X = (const float*)d_in[0];      // [4,2048,64]
  const float* qkv_w = (const float*)d_in[1];  // [64,3072]
  const float* qkv_b = (const float*)d_in[2];  // [3072]
  const float* out_w = (const float*)d_in[3];  // [1024,64]
  const float* out_b = (const float*)d_in[4];  // [64]
  float* out = (float*)d_out;

  const size_t NE = (size_t)B_ * H_ * N_ * D_;  // 8388608 elems per array
  unsigned short* ws16 = (unsigned short*)d_ws;
  unsigned short* Qhi = ws16 + 0 * NE;
  unsigned short* Khi = ws16 + 1 * NE;
  unsigned short* VThi = ws16 + 2 * NE;   // transposed [B][H][D][N], key-permuted
  unsigned short* ctxHi = ws16 + 3 * NE;  // [8192][1024] bf16
  unsigned short* ctxLo = ws16 + 4 * NE;
  unsigned short* W2THi = ws16 + 5 * NE;  // [64][1024] bf16
  unsigned short* W2TLo = W2THi + 65536;

  qkv_kernel<<<dim3(25, 64), 256, 0, stream>>>(X, qkv_w, qkv_b, out_w, Qhi,
                                               Khi, VThi, W2THi, W2TLo);
  attn_kernel<<<1024, 256, 0, stream>>>(Qhi, Khi, VThi, ctxHi, ctxLo);
  out_kernel<<<512, 256, 0, stream>>>(ctxHi, ctxLo, W2THi, W2TLo, out_b, out);
}